// Round 4
// baseline (27.754 us; speedup 1.0000x reference)
//
#include <hip/hip_runtime.h>
#include <hip/hip_bf16.h>

#define HH 512
#define LL 1024
#define CC 512
#define NREL 51

typedef __attribute__((ext_vector_type(8))) short bf16x8;
typedef __attribute__((ext_vector_type(4))) float f32x4;
typedef __attribute__((ext_vector_type(2))) float f32x2;

__device__ __forceinline__ short f2bn(float f) {
    return __builtin_bit_cast(short, __float2bfloat16(f));   // native RNE cvt
}

// async global->LDS, 16B per lane; lds arg = wave-uniform base (lane i lands at +16i)
__device__ __forceinline__ void gl16(const void* g, void* l) {
    __builtin_amdgcn_global_load_lds(
        (const __attribute__((address_space(1))) void*)g,
        (__attribute__((address_space(3))) void*)l, 16, 0, 0);
}

// ---------------------------------------------------------------------------
// K1: FUSED k0+k1. 768 blocks x 256 threads (4 waves).
// Block: 16x64 tile of q = query@Wq.T + bq (b<512) or k = key@Wk.T (b>=512).
// Phase 1: cooperative reg-staging — load f32 A(16x512)+B(64x512) slices, cvt
//   to bf16, write LDS with the per-row chunk-XOR swizzle (T2/T21 layout).
// Phase 2: wave w computes the full 16x64 tile over K-quarter [128w,128w+128)
//   (2 BK=64 steps, 16 MFMA), then LDS reduce (R3-proven pattern).
// Phase 3 (q-blocks): wave 0 writes swizzled qbuf + q-tile to LDS A-layout;
//   waves 1-3 reg-stage relk f32 (rows>=51 zeroed) to LDS B-layout; wave 0
//   does one K=64 MFMA step for the R-partial and writes Rpart slot (b&7)
//   NON-atomically — every slot cell rewritten each replay, no zeroing needed.
// ---------------------------------------------------------------------------
__global__ __launch_bounds__(256) void k1_proj(
    const float* __restrict__ query, const float* __restrict__ key,
    const float* __restrict__ Wq, const float* __restrict__ Wk,
    const float* __restrict__ relk, const float* __restrict__ bq,
    short* __restrict__ qbuf, short* __restrict__ kbuf,
    float* __restrict__ Rpart)
{
    __shared__ __align__(16) short Alds[16 * 512];   // 16 KB
    __shared__ __align__(16) short Blds[64 * 512];   // 64 KB
    const int b = blockIdx.x, tid = threadIdx.x;
    const int w = tid >> 6, lane = tid & 63;
    const bool isq = (b < 512);
    const float *A, *B; short* outp; int m0, n0;
    if (isq) { A = query; B = Wq; outp = qbuf;
               m0 = (b >> 3) * 16; n0 = (b & 7) * 64; }
    else     { const int bb = b - 512; A = key; B = Wk; outp = kbuf;
               m0 = (bb >> 3) * 16; n0 = (bb & 7) * 64; }

    // ---- phase 1: cooperative f32 -> bf16 staging, XOR-swizzled ----
    {
        const int ar = tid >> 4, ac = (tid & 15) * 8;     // A: 16 rows, 8-col spans
        #pragma unroll
        for (int j = 0; j < 4; ++j) {
            const int c = ac + j * 128;
            float4 x = *(const float4*)(A + (m0 + ar) * HH + c);
            float4 y = *(const float4*)(A + (m0 + ar) * HH + c + 4);
            bf16x8 o;
            o[0] = f2bn(x.x); o[1] = f2bn(x.y); o[2] = f2bn(x.z); o[3] = f2bn(x.w);
            o[4] = f2bn(y.x); o[5] = f2bn(y.y); o[6] = f2bn(y.z); o[7] = f2bn(y.w);
            *(bf16x8*)(Alds + ar * 512 + (((c >> 3) ^ (ar & 7)) << 3)) = o;
        }
        const int br = tid >> 2, bc = (tid & 3) * 16;     // B: 64 rows, 16-col spans
        #pragma unroll
        for (int j = 0; j < 8; ++j) {
            const int c = bc + j * 64;
            float4 x0 = *(const float4*)(B + (n0 + br) * HH + c);
            float4 x1 = *(const float4*)(B + (n0 + br) * HH + c + 4);
            float4 x2 = *(const float4*)(B + (n0 + br) * HH + c + 8);
            float4 x3 = *(const float4*)(B + (n0 + br) * HH + c + 12);
            bf16x8 o0, o1;
            o0[0] = f2bn(x0.x); o0[1] = f2bn(x0.y); o0[2] = f2bn(x0.z); o0[3] = f2bn(x0.w);
            o0[4] = f2bn(x1.x); o0[5] = f2bn(x1.y); o0[6] = f2bn(x1.z); o0[7] = f2bn(x1.w);
            o1[0] = f2bn(x2.x); o1[1] = f2bn(x2.y); o1[2] = f2bn(x2.z); o1[3] = f2bn(x2.w);
            o1[4] = f2bn(x3.x); o1[5] = f2bn(x3.y); o1[6] = f2bn(x3.z); o1[7] = f2bn(x3.w);
            *(bf16x8*)(Blds + br * 512 + ((((c >> 3) + 0) ^ (br & 7)) << 3)) = o0;
            *(bf16x8*)(Blds + br * 512 + ((((c >> 3) + 1) ^ (br & 7)) << 3)) = o1;
        }
    }
    __syncthreads();

    // ---- phase 2: per-wave K-quarter GEMM ----
    const int lr = lane & 15, lk = (lane >> 4) * 8;
    const int lx = 8 * (lr & 7);
    f32x4 acc[4] = {};
    #pragma unroll
    for (int t = 0; t < 2; ++t) {
        const int k0g = w * 128 + t * 64;
        bf16x8 a0 = *(const bf16x8*)(Alds + lr * 512 + k0g + ((0 + lk) ^ lx));
        bf16x8 a1 = *(const bf16x8*)(Alds + lr * 512 + k0g + ((32 + lk) ^ lx));
        #pragma unroll
        for (int f = 0; f < 4; ++f) {
            const int ro = (f * 16 + lr) * 512 + k0g;
            bf16x8 b0 = *(const bf16x8*)(Blds + ro + ((0 + lk) ^ lx));
            bf16x8 b1 = *(const bf16x8*)(Blds + ro + ((32 + lk) ^ lx));
            acc[f] = __builtin_amdgcn_mfma_f32_16x16x32_bf16(a0, b0, acc[f], 0, 0, 0);
            acc[f] = __builtin_amdgcn_mfma_f32_16x16x32_bf16(a1, b1, acc[f], 0, 0, 0);
        }
    }
    __syncthreads();                       // stage LDS now dead everywhere

    float* P = (float*)Blds;               // partials park in dead B area
    if (w) {
        #pragma unroll
        for (int f = 0; f < 4; ++f)
            *(f32x4*)(P + (w - 1) * 1024 + lane * 16 + f * 4) = acc[f];
    }
    __syncthreads();

    short* qt   = Blds + 8192;             // q-tile in A-frag layout (1024 sh)
    short* Brel = Blds + 16384;            // relk tile in B-frag layout (4096 sh)
    if (w == 0) {
        #pragma unroll
        for (int wv = 0; wv < 3; ++wv)
            #pragma unroll
            for (int f = 0; f < 4; ++f)
                acc[f] += *(const f32x4*)(P + wv * 1024 + lane * 16 + f * 4);
        #pragma unroll
        for (int f = 0; f < 4; ++f) {
            const int colg = f * 16 + lr;
            const float bv = isq ? bq[n0 + colg] : 0.f;
            #pragma unroll
            for (int r = 0; r < 4; ++r) {
                const int row = (lane >> 4) * 4 + r;
                const short h = f2bn(acc[f][r] + bv);
                outp[(m0 + row) * HH + n0 + (colg ^ (8 * (row & 7)))] = h;
                if (isq)
                    qt[row * 64 + (((colg >> 3) ^ (row & 7)) << 3) + (colg & 7)] = h;
            }
        }
    } else if (isq) {
        // waves 1-3: reg-stage relk slice [64 rel x 64 h], rows >= NREL zeroed
        for (int i = tid - 64; i < 1024; i += 192) {
            const int rr = i >> 4, c4 = (i & 15) * 4;
            float4 v = make_float4(0.f, 0.f, 0.f, 0.f);
            if (rr < NREL) v = *(const float4*)(relk + rr * HH + n0 + c4);
            short4 o;
            o.x = f2bn(v.x); o.y = f2bn(v.y); o.z = f2bn(v.z); o.w = f2bn(v.w);
            *(short4*)(Brel + rr * 64 + (((c4 >> 3) ^ (rr & 7)) << 3) + (c4 & 7)) = o;
        }
    }
    __syncthreads();

    if (w == 0 && isq) {                   // R-partial: q-tile @ relk-slice^T
        bf16x8 a0 = *(const bf16x8*)(qt + lr * 64 + ((0 + lk) ^ lx));
        bf16x8 a1 = *(const bf16x8*)(qt + lr * 64 + ((32 + lk) ^ lx));
        f32x4 racc[4] = {};
        #pragma unroll
        for (int f = 0; f < 4; ++f) {
            const int ro = (f * 16 + lr) * 64;
            bf16x8 b0 = *(const bf16x8*)(Brel + ro + ((0 + lk) ^ lx));
            bf16x8 b1 = *(const bf16x8*)(Brel + ro + ((32 + lk) ^ lx));
            racc[f] = __builtin_amdgcn_mfma_f32_16x16x32_bf16(a0, b0, racc[f], 0, 0, 0);
            racc[f] = __builtin_amdgcn_mfma_f32_16x16x32_bf16(a1, b1, racc[f], 0, 0, 0);
        }
        #pragma unroll
        for (int f = 0; f < 4; ++f)
            #pragma unroll
            for (int r = 0; r < 4; ++r)
                Rpart[(b & 7) * (LL * 64) + (m0 + (lane >> 4) * 4 + r) * 64 + f * 16 + lr]
                    = racc[f][r];
    }
}

// ---------------------------------------------------------------------------
// K2: FUSED k2+k3. 64 blocks x 512 threads (8 waves). Block owns 16 FULL rows;
// wave w = col-group w (64 cols), full K=512 as 8 BK=64 steps, depth-1 counted
// vmcnt(10) pipeline. A-fragments load DIRECTLY from swizzled qbuf into regs
// (verified identical to the LDS round-trip); only k-tiles stage via gl16
// (8/step). Prologue issues Rpart 8-slot loads + rel idx loads as the oldest
// vmem — drained for free by the loop's final vmcnt(0). Post-loop: sum slots
// into Rs, LDS-gather, exp, cross-wave psum reduce, and write the FINAL
// normalized softmax — no k3, no Ssum, no fences, no atomics.
// ---------------------------------------------------------------------------
__global__ __launch_bounds__(512) void k2_attn(
    const short* __restrict__ qbuf, const short* __restrict__ kbuf,
    const int* __restrict__ rel, const int* __restrict__ qlen,
    const float* __restrict__ Rpart, float* __restrict__ out)
{
    __shared__ __align__(16) short Bb[8][2][4096];   // 128 KB: per-wave dbuf
    __shared__ float Rs[16][64];                     // 4 KB
    __shared__ float psum[8][16];                    // 512 B
    const int b = blockIdx.x, tid = threadIdx.x;
    const int w = tid >> 6, lane = tid & 63;
    const int l0 = b * 16, cb = w * 64;
    const int lr = lane & 15, lk = (lane >> 4) * 8;
    const int lx = 8 * (lr & 7);
    const int srow = lane >> 3, scol = (lane & 7) * 8;
    const int qoff = qlen[0];

    // prologue (oldest vmem): R slots (8 x dwordx2) + rel indices (16 x dword)
    const int rrow = tid >> 5, rc = (tid & 31) * 2;
    f32x2 rpv[8];
    #pragma unroll
    for (int p = 0; p < 8; ++p)
        rpv[p] = *(const f32x2*)(Rpart + p * (LL * 64) + (l0 + rrow) * 64 + rc);
    int idxr[4][4];
    #pragma unroll
    for (int r = 0; r < 4; ++r) {
        const int row = (lane >> 4) * 4 + r;
        #pragma unroll
        for (int f = 0; f < 4; ++f)
            idxr[r][f] = rel[(l0 + row) * LL + qoff + cb + f * 16 + lr];
    }
    __builtin_amdgcn_sched_barrier(0);

    bf16x8 a0v[2], a1v[2];
#define K2_STAGE(bi, t) do { \
        const int k0g = (t) * 64; \
        short* Lb = &Bb[w][bi][0]; \
        _Pragma("unroll") \
        for (int j = 0; j < 8; ++j) \
            gl16(kbuf + (cb + j * 8 + srow) * HH + k0g + scol, Lb + j * 512); \
        a0v[bi] = *(const bf16x8*)(qbuf + (l0 + lr) * HH + k0g + ((0 + lk) ^ lx)); \
        a1v[bi] = *(const bf16x8*)(qbuf + (l0 + lr) * HH + k0g + ((32 + lk) ^ lx)); \
    } while (0)

    f32x4 acc[4] = {};
#define K2_COMP(bi) do { \
        const short* Lb = &Bb[w][bi][0]; \
        _Pragma("unroll") \
        for (int f = 0; f < 4; ++f) { \
            const int ro = (f * 16 + lr) * 64; \
            bf16x8 k0f = *(const bf16x8*)(Lb + ro + ((0 + lk) ^ lx)); \
            bf16x8 k1f = *(const bf16x8*)(Lb + ro + ((32 + lk) ^ lx)); \
            acc[f] = __builtin_amdgcn_mfma_f32_16x16x32_bf16(a0v[bi], k0f, acc[f], 0, 0, 0); \
            acc[f] = __builtin_amdgcn_mfma_f32_16x16x32_bf16(a1v[bi], k1f, acc[f], 0, 0, 0); \
        } \
    } while (0)

    K2_STAGE(0, 0);
    #pragma unroll
    for (int t = 0; t < 8; ++t) {
        if (t < 7) {
            K2_STAGE((t + 1) & 1, t + 1);
            asm volatile("s_waitcnt vmcnt(10)" ::: "memory");   // step t landed
        } else {
            asm volatile("s_waitcnt vmcnt(0)" ::: "memory");    // drains prologue too
        }
        __builtin_amdgcn_sched_barrier(0);
        K2_COMP(t & 1);
    }
#undef K2_STAGE
#undef K2_COMP

    // R slot-sum -> Rs (rpv regs valid: vmcnt(0) above)
    float rx = 0.f, ry = 0.f;
    #pragma unroll
    for (int p = 0; p < 8; ++p) { rx += rpv[p][0]; ry += rpv[p][1]; }
    Rs[rrow][rc] = rx; Rs[rrow][rc + 1] = ry;
    __syncthreads();

    const float scale = 0.04419417382415922f;   // 1/sqrt(512)
    #pragma unroll
    for (int r = 0; r < 4; ++r) {
        const int row = (lane >> 4) * 4 + r;
        float s = 0.f;
        #pragma unroll
        for (int f = 0; f < 4; ++f) {
            float e = __expf((acc[f][r] + Rs[row][idxr[r][f]]) * scale);
            acc[f][r] = e; s += e;
        }
        #pragma unroll
        for (int sh = 1; sh < 16; sh <<= 1) s += __shfl_xor(s, sh, 64);
        if (lr == 0) psum[w][row] = s;
    }
    __syncthreads();
    #pragma unroll
    for (int r = 0; r < 4; ++r) {
        const int row = (lane >> 4) * 4 + r;
        float tot = 0.f;
        #pragma unroll
        for (int wv = 0; wv < 8; ++wv) tot += psum[wv][row];
        const float inv = 1.f / tot;
        #pragma unroll
        for (int f = 0; f < 4; ++f)
            out[(l0 + row) * CC + cb + f * 16 + lr] = acc[f][r] * inv;
    }
}

extern "C" void kernel_launch(void* const* d_in, const int* in_sizes, int n_in,
                              void* d_out, int out_size, void* d_ws, size_t ws_size,
                              hipStream_t stream) {
    const float* query = (const float*)d_in[0];
    const float* key   = (const float*)d_in[1];
    const int*   rel   = (const int*)d_in[3];
    const int*   qlen  = (const int*)d_in[4];
    const float* Wq    = (const float*)d_in[6];
    const float* bq    = (const float*)d_in[7];
    const float* Wk    = (const float*)d_in[8];
    const float* relk  = (const float*)d_in[12];

    float* out = (float*)d_out;
    short* p = (short*)d_ws;
    short* qbuf  = p;  p += LL * HH;         // 1 MB bf16, pre-swizzled
    short* kbuf  = p;  p += CC * HH;         // 512 KB bf16, pre-swizzled
    float* Rpart = (float*)p;                // 8 x 1024 x 64 f32 = 2 MB

    k1_proj<<<768, 256, 0, stream>>>(query, key, Wq, Wk, relk, bq,
                                     qbuf, kbuf, Rpart);
    k2_attn<<<64, 512, 0, stream>>>(qbuf, kbuf, rel, qlen, Rpart, out);
}

// Round 5
// 27.189 us; speedup vs baseline: 1.0208x; 1.0208x over previous
//
#include <hip/hip_runtime.h>
#include <hip/hip_bf16.h>

#define HH 512
#define LL 1024
#define CC 512
#define NREL 51

typedef __attribute__((ext_vector_type(8))) short bf16x8;
typedef __attribute__((ext_vector_type(4))) float f32x4;

__device__ __forceinline__ short f2bn(float f) {
    return __builtin_bit_cast(short, __float2bfloat16(f));   // native RNE cvt
}

// 8 consecutive f32 -> bf16x8 (RNE), 16B-aligned source
__device__ __forceinline__ bf16x8 cvt8(const float* p) {
    float4 x = *(const float4*)p;
    float4 y = *(const float4*)(p + 4);
    bf16x8 o;
    o[0] = f2bn(x.x); o[1] = f2bn(x.y); o[2] = f2bn(x.z); o[3] = f2bn(x.w);
    o[4] = f2bn(y.x); o[5] = f2bn(y.y); o[6] = f2bn(y.z); o[7] = f2bn(y.w);
    return o;
}

// ---------------------------------------------------------------------------
// K1: projections q = query@Wq.T + bq (blocks 0..127), k = key@Wk.T
// (blocks 128..191; bk softmax-invariant, dropped). Block = 64x64 output tile,
// 512 thr / 8 waves = 4 m-subtiles x 2 K-halves. B (weights) staged ONCE per
// block f32->bf16 chunk-XOR-swizzled LDS (64 KB); A-frags converted from f32
// directly in registers (no A staging). K-half partials reduced through the
// (dead) B LDS. Outputs stored pre-swizzled bf16 for K2's register-direct
// frag loads. Block 192: relkb prep (64x512 bf16 swizzled, rows>=51 zeroed).
// Weight traffic 24.6 MB + A 24.6 MB (vs R4's 123 MB).
// ---------------------------------------------------------------------------
__global__ __launch_bounds__(512) void k1_proj(
    const float* __restrict__ query, const float* __restrict__ key,
    const float* __restrict__ Wq, const float* __restrict__ Wk,
    const float* __restrict__ relk, const float* __restrict__ bq,
    short* __restrict__ qbuf, short* __restrict__ kbuf,
    short* __restrict__ relkb)
{
    const int b = blockIdx.x, tid = threadIdx.x;
    if (b == 192) {     // relkb: 64 rel-rows x 512 h, swizzled, tail zeroed
        for (int i = tid; i < 64 * 64; i += 512) {
            const int rr = i >> 6, c8 = i & 63;
            bf16x8 o = {};
            if (rr < NREL) o = cvt8(relk + rr * HH + c8 * 8);
            *(bf16x8*)(relkb + rr * HH + ((c8 ^ (rr & 7)) << 3)) = o;
        }
        return;
    }
    __shared__ __align__(16) short Blds[64 * 512];   // 64 KB
    const int w = tid >> 6, lane = tid & 63;
    const int ms = w >> 1, ks = w & 1;               // 4 m-subtiles x 2 K-halves
    const bool isq = (b < 128);
    const float *A, *B; short* outp; int m0, n0;
    if (isq) { A = query; B = Wq; outp = qbuf;
               m0 = (b >> 3) * 64; n0 = (b & 7) * 64; }
    else     { const int bb = b - 128; A = key; B = Wk; outp = kbuf;
               m0 = (bb >> 3) * 64; n0 = (bb & 7) * 64; }

    // stage B rows n0..n0+64 (512 cols) f32 -> bf16, chunk-XOR swizzle
    {
        const int br = tid >> 3, cbase = tid & 7;
        #pragma unroll
        for (int j = 0; j < 8; ++j) {
            const int c8 = cbase + j * 8;
            bf16x8 o = cvt8(B + (n0 + br) * HH + c8 * 8);
            *(bf16x8*)(Blds + br * 512 + ((c8 ^ (br & 7)) << 3)) = o;
        }
    }
    __syncthreads();

    const int lr = lane & 15, lk = (lane >> 4) * 8;
    const int lx = 8 * (lr & 7);
    const int arow = m0 + ms * 16 + lr;
    f32x4 acc[4] = {};
    #pragma unroll
    for (int t = 0; t < 4; ++t) {
        const int k0g = ks * 256 + t * 64;
        bf16x8 a0 = cvt8(A + arow * HH + k0g + lk);
        bf16x8 a1 = cvt8(A + arow * HH + k0g + 32 + lk);
        #pragma unroll
        for (int f = 0; f < 4; ++f) {
            const int ro = (f * 16 + lr) * 512 + k0g;
            bf16x8 b0 = *(const bf16x8*)(Blds + ro + ((0 + lk) ^ lx));
            bf16x8 b1 = *(const bf16x8*)(Blds + ro + ((32 + lk) ^ lx));
            acc[f] = __builtin_amdgcn_mfma_f32_16x16x32_bf16(a0, b0, acc[f], 0, 0, 0);
            acc[f] = __builtin_amdgcn_mfma_f32_16x16x32_bf16(a1, b1, acc[f], 0, 0, 0);
        }
    }
    __syncthreads();                     // B LDS dead; reuse for K-half reduce
    float* P = (float*)Blds;             // 4 ms x 64 lanes x 16 f32 = 16 KB
    if (ks) {
        #pragma unroll
        for (int f = 0; f < 4; ++f)
            *(f32x4*)(P + (ms * 64 + lane) * 16 + f * 4) = acc[f];
    }
    __syncthreads();
    if (!ks) {
        #pragma unroll
        for (int f = 0; f < 4; ++f)
            acc[f] += *(const f32x4*)(P + (ms * 64 + lane) * 16 + f * 4);
        #pragma unroll
        for (int f = 0; f < 4; ++f) {
            const int colg = f * 16 + lr;
            const float bv = isq ? bq[n0 + colg] : 0.f;
            #pragma unroll
            for (int r = 0; r < 4; ++r) {
                const int row = ms * 16 + (lane >> 4) * 4 + r;
                outp[(m0 + row) * HH + n0 + (colg ^ (8 * (row & 7)))]
                    = f2bn(acc[f][r] + bv);
            }
        }
    }
}

// ---------------------------------------------------------------------------
// K2: 64 blocks x 512 thr (8 waves); block owns 16 FULL rows -> softmax +
// normalization complete in-block (no k3, no fences). Wave w = col-group w:
// QK over K=512 as 8 BK=64 steps, register-direct A/B frags from swizzled
// qbuf/kbuf (no LDS staging, no asm waits), depth-3 rotating pipeline.
// R = q@relk^T computed ONCE per block: wave w does K-slice [64w,64w+64)
// (8 relkb frags + 8 MFMA), partials reduced via LDS -> Rs[16][64].
// Epilogue: rel-gather from Rs, exp, cross-wave psum, normalized out.
// ---------------------------------------------------------------------------
__global__ __launch_bounds__(512) void k2_attn(
    const short* __restrict__ qbuf, const short* __restrict__ kbuf,
    const short* __restrict__ relkb, const int* __restrict__ rel,
    const int* __restrict__ qlen, float* __restrict__ out)
{
    __shared__ float Rpark[8][16][64];   // 32 KB
    __shared__ float Rs[16][64];         // 4 KB
    __shared__ float psum[8][16];        // 512 B
    const int b = blockIdx.x, tid = threadIdx.x;
    const int w = tid >> 6, lane = tid & 63;
    const int l0 = b * 16, cb = w * 64;
    const int lr = lane & 15, lk = (lane >> 4) * 8;
    const int lx = 8 * (lr & 7);
    const int qoff = qlen[0];

    // rel gather indices first (consumed only in the epilogue)
    int idxr[4][4];
    #pragma unroll
    for (int r = 0; r < 4; ++r) {
        const int row = (lane >> 4) * 4 + r;
        #pragma unroll
        for (int f = 0; f < 4; ++f)
            idxr[r][f] = rel[(l0 + row) * LL + qoff + cb + f * 16 + lr];
    }

    f32x4 acc[4] = {};
    bf16x8 a0v[3], a1v[3], kbv[3][8];
#define K2_LOAD(bi, t) do { \
        const int k0g = (t) * 64; \
        a0v[bi] = *(const bf16x8*)(qbuf + (l0 + lr) * HH + k0g + ((0 + lk) ^ lx)); \
        a1v[bi] = *(const bf16x8*)(qbuf + (l0 + lr) * HH + k0g + ((32 + lk) ^ lx)); \
        _Pragma("unroll") \
        for (int f = 0; f < 4; ++f) { \
            kbv[bi][2*f]   = *(const bf16x8*)(kbuf + (cb + f*16 + lr) * HH + k0g + ((0 + lk) ^ lx)); \
            kbv[bi][2*f+1] = *(const bf16x8*)(kbuf + (cb + f*16 + lr) * HH + k0g + ((32 + lk) ^ lx)); \
        } } while (0)
#define K2_COMP(bi) do { \
        _Pragma("unroll") \
        for (int f = 0; f < 4; ++f) { \
            acc[f] = __builtin_amdgcn_mfma_f32_16x16x32_bf16(a0v[bi], kbv[bi][2*f],   acc[f], 0, 0, 0); \
            acc[f] = __builtin_amdgcn_mfma_f32_16x16x32_bf16(a1v[bi], kbv[bi][2*f+1], acc[f], 0, 0, 0); \
        } } while (0)

    K2_LOAD(0, 0); K2_LOAD(1, 1);
    #pragma unroll
    for (int t = 0; t < 8; ++t) {
        if (t < 6) K2_LOAD((t + 2) % 3, t + 2);
        K2_COMP(t % 3);
    }
#undef K2_LOAD
#undef K2_COMP

    // R K-slice [64w, 64w+64): A from qbuf (L1/L2-hot), B from relkb
    {
        const int k0g = w * 64;
        bf16x8 a0 = *(const bf16x8*)(qbuf + (l0 + lr) * HH + k0g + ((0 + lk) ^ lx));
        bf16x8 a1 = *(const bf16x8*)(qbuf + (l0 + lr) * HH + k0g + ((32 + lk) ^ lx));
        f32x4 racc[4] = {};
        #pragma unroll
        for (int f = 0; f < 4; ++f) {
            const int ro = (f * 16 + lr) * HH + k0g;
            bf16x8 b0 = *(const bf16x8*)(relkb + ro + ((0 + lk) ^ lx));
            bf16x8 b1 = *(const bf16x8*)(relkb + ro + ((32 + lk) ^ lx));
            racc[f] = __builtin_amdgcn_mfma_f32_16x16x32_bf16(a0, b0, racc[f], 0, 0, 0);
            racc[f] = __builtin_amdgcn_mfma_f32_16x16x32_bf16(a1, b1, racc[f], 0, 0, 0);
        }
        #pragma unroll
        for (int f = 0; f < 4; ++f)
            #pragma unroll
            for (int r = 0; r < 4; ++r)
                Rpark[w][(lane >> 4) * 4 + r][f * 16 + lr] = racc[f][r];
    }
    __syncthreads();
    // wave w sums rows 2w, 2w+1 across the 8 K-slice partials
    #pragma unroll
    for (int rr = 0; rr < 2; ++rr) {
        const int row = w * 2 + rr;
        float s = 0.f;
        #pragma unroll
        for (int pp = 0; pp < 8; ++pp) s += Rpark[pp][row][lane];
        Rs[row][lane] = s;
    }
    __syncthreads();

    const float scale = 0.04419417382415922f;   // 1/sqrt(512)
    #pragma unroll
    for (int r = 0; r < 4; ++r) {
        const int row = (lane >> 4) * 4 + r;
        float s = 0.f;
        #pragma unroll
        for (int f = 0; f < 4; ++f) {
            float e = __expf((acc[f][r] + Rs[row][idxr[r][f]]) * scale);
            acc[f][r] = e; s += e;
        }
        #pragma unroll
        for (int sh = 1; sh < 16; sh <<= 1) s += __shfl_xor(s, sh, 64);
        if (lr == 0) psum[w][row] = s;
    }
    __syncthreads();
    #pragma unroll
    for (int r = 0; r < 4; ++r) {
        const int row = (lane >> 4) * 4 + r;
        float tot = 0.f;
        #pragma unroll
        for (int wv = 0; wv < 8; ++wv) tot += psum[wv][row];
        const float inv = 1.f / tot;
        #pragma unroll
        for (int f = 0; f < 4; ++f)
            out[(l0 + row) * CC + cb + f * 16 + lr] = acc[f][r] * inv;
    }
}

extern "C" void kernel_launch(void* const* d_in, const int* in_sizes, int n_in,
                              void* d_out, int out_size, void* d_ws, size_t ws_size,
                              hipStream_t stream) {
    const float* query = (const float*)d_in[0];
    const float* key   = (const float*)d_in[1];
    const int*   rel   = (const int*)d_in[3];
    const int*   qlen  = (const int*)d_in[4];
    const float* Wq    = (const float*)d_in[6];
    const float* bq    = (const float*)d_in[7];
    const float* Wk    = (const float*)d_in[8];
    const float* relk  = (const float*)d_in[12];

    float* out = (float*)d_out;
    short* p = (short*)d_ws;
    short* qbuf  = p;  p += LL * HH;     // 1 MB bf16, pre-swizzled
    short* kbuf  = p;  p += CC * HH;     // 512 KB bf16, pre-swizzled
    short* relkb = p;  p += 64 * HH;     // 64 KB bf16, swizzled, tail zeroed

    k1_proj<<<193, 512, 0, stream>>>(query, key, Wq, Wk, relk, bq,
                                     qbuf, kbuf, relkb);
    k2_attn<<<64, 512, 0, stream>>>(qbuf, kbuf, relkb, rel, qlen, out);
}